// Round 18
// baseline (48.228 us; speedup 1.0000x reference)
//
#include <hip/hip_runtime.h>
#include <hip/hip_bf16.h>

#define J_DIM 25
#define T_DIM 120
#define O_DIM 64
#define KPAD  328        // bf16 per ys/Wf row; 656 B = 41*16 (b128-aligned)
#define HROWS 60         // t-rows per sub-chunk (two sub-chunks per block)
#define XROWS 124        // whole-sequence window rows: row i = x[clamp(i-2)]
#define XPAD  20         // xs row pad (floats); 4q offsets stay 16B-aligned

typedef __attribute__((ext_vector_type(8))) short bf16x8;
typedef __attribute__((ext_vector_type(4))) float f32x4;

__device__ __forceinline__ unsigned f2bf(float f) {
    union { float f; unsigned u; } v; v.f = f;
    return (v.u + 0x7FFFu + ((v.u >> 16) & 1u)) >> 16;
}
__device__ __forceinline__ unsigned pk2(float lo, float hi) {
    __hip_bfloat162 h = __float22bfloat162_rn(float2{lo, hi});
    unsigned u;
    __builtin_memcpy(&u, &h, 4);
    return u;
}

// ---- W (306x64 f32) -> Wf[o][k], k = 18a + b; b<17: 0.5*W2[a,b]; b==17: W1[a] ----
__global__ void wprep(const float* __restrict__ W, unsigned short* __restrict__ Wf) {
    int i = blockIdx.x * 256 + threadIdx.x;
    if (i >= O_DIM * KPAD) return;
    int o = i / KPAD, k = i % KPAD;
    int a = k / 18, b = k % 18;
    float v = 0.0f;
    if (k < 306) v = (b == 17) ? W[a * O_DIM + o] : 0.5f * W[(17 + 17 * a + b) * O_DIM + o];
    Wf[o * KPAD + k] = (unsigned short)f2bf(v);
}

// ---- main: block = (n, j); stage x once; two unrolled 60-row sub-chunks ----
// Baked-in lessons: launch_bounds must never clamp VGPR below need (R6/R10);
// phase bodies straight-line, no loop-carried live state (R8/R9/R13 spills);
// B-frag register reuse only inside the short phase-2 scope (R14).
__global__ __launch_bounds__(256, 2) void sig_mfma(
    const float* __restrict__ x, const unsigned short* __restrict__ Wf,
    const float* __restrict__ bias, float* __restrict__ out)
{
    __shared__ float xs[XROWS][XPAD];            // 9,920 B
    __shared__ unsigned short ys[HROWS * KPAD];  // 39,360 B  (total 49.3 KB -> 3 blk/CU)

    const int tid = threadIdx.x;
    const int j = blockIdx.x % J_DIM;
    const int n = blockIdx.x / J_DIM;
    const int wave = tid >> 6, lane = tid & 63;
    const int l15 = lane & 15, l4 = lane >> 4;

    // ---- stage xs[i][c] = x[n,c,j,clamp(i-2)] once for the whole sequence ----
    const float* xbase = x + ((size_t)(n * 16) * J_DIM + j) * T_DIM;
    for (int idx = tid; idx < 16 * XROWS; idx += 256) {
        int c = idx / XROWS, i = idx % XROWS;
        int st = min(max(i - 2, 0), T_DIM - 1);
        xs[i][c] = xbase[(size_t)c * J_DIM * T_DIM + st];
    }
    // zero pad bytes [608,656) of rows 0..59 (608-611 re-written by time-row store)
    if (tid < HROWS * 3) {
        int r = tid / 3, p = tid % 3;
        *(uint4*)((char*)ys + r * 656 + 608 + p * 16) = uint4{0, 0, 0, 0};
    }
    __syncthreads();

    #pragma unroll
    for (int half = 0; half < 2; ++half) {
        const int t0 = half * HROWS;

        // ---- phase 1: one slot per thread: (row = tid>>2 < 60, q = tid&3) ----
        // S2[a,b] = sum_w h_w[a]*p_w[b], h = (-p1, p0-p2, p1-p3, p2-p4, p3+p4)
        // q==3 additionally computes time row a=16 (once per t).
        if (tid < HROWS * 4) {
            const int row = tid >> 2, q = tid & 3;
            const int t = t0 + row;
            const int start = max(t - 2, 0), end = min(t + 3, T_DIM);
            const float inv = 1.0f / (float)(end - start - 1);
            const bool doT = (q == 3);
            float ptv[5];
            #pragma unroll
            for (int w = 0; w < 5; ++w) {
                int pcw = min(max(t - 2 + w, 0), T_DIM - 1);
                ptv[w] = (float)(pcw - start) * inv;
            }
            const int xr = t0 + row;
            float4 paw[5];                       // window row w: a-rows 4q..4q+3
            #pragma unroll
            for (int w = 0; w < 5; ++w)
                paw[w] = *(const float4*)&xs[xr + w][4 * q];

            float h0[5], h1[5], h2[5], h3[5], ht[5];
            h0[0] = -paw[1].x;           h1[0] = -paw[1].y;           h2[0] = -paw[1].z;           h3[0] = -paw[1].w;
            h0[1] = paw[0].x - paw[2].x; h1[1] = paw[0].y - paw[2].y; h2[1] = paw[0].z - paw[2].z; h3[1] = paw[0].w - paw[2].w;
            h0[2] = paw[1].x - paw[3].x; h1[2] = paw[1].y - paw[3].y; h2[2] = paw[1].z - paw[3].z; h3[2] = paw[1].w - paw[3].w;
            h0[3] = paw[2].x - paw[4].x; h1[3] = paw[2].y - paw[4].y; h2[3] = paw[2].z - paw[4].z; h3[3] = paw[2].w - paw[4].w;
            h0[4] = paw[3].x + paw[4].x; h1[4] = paw[3].y + paw[4].y; h2[4] = paw[3].z + paw[4].z; h3[4] = paw[3].w + paw[4].w;
            if (doT) {
                ht[0] = -ptv[1];
                ht[1] = ptv[0] - ptv[2];
                ht[2] = ptv[1] - ptv[3];
                ht[3] = ptv[2] - ptv[4];
                ht[4] = ptv[3] + ptv[4];
            }

            unsigned u0[9], u1[9], u2[9], u3[9], ut[9];
            float ac0 = 0, ac1 = 0, ac2 = 0, ac3 = 0, act = 0;
            #pragma unroll
            for (int hb = 0; hb < 2; ++hb) {
                float4 xw[5][2];
                #pragma unroll
                for (int w = 0; w < 5; ++w) {
                    const float* rw = &xs[xr + w][0];
                    xw[w][0] = *(const float4*)(rw + 8 * hb);
                    xw[w][1] = *(const float4*)(rw + 8 * hb + 4);
                }
                #pragma unroll
                for (int b8 = 0; b8 < 8; ++b8) {
                    float pb[5];
                    #pragma unroll
                    for (int w = 0; w < 5; ++w) {
                        float4 v = xw[w][b8 >> 2];
                        pb[w] = ((b8 & 3) == 0) ? v.x : ((b8 & 3) == 1) ? v.y
                              : ((b8 & 3) == 2) ? v.z : v.w;
                    }
                    float a0 = h0[0] * pb[0], a1 = h1[0] * pb[0];
                    float a2 = h2[0] * pb[0], a3 = h3[0] * pb[0];
                    #pragma unroll
                    for (int w = 1; w < 5; ++w) {
                        a0 = fmaf(h0[w], pb[w], a0);
                        a1 = fmaf(h1[w], pb[w], a1);
                        a2 = fmaf(h2[w], pb[w], a2);
                        a3 = fmaf(h3[w], pb[w], a3);
                    }
                    float at = 0;
                    if (doT) {
                        at = ht[0] * pb[0];
                        #pragma unroll
                        for (int w = 1; w < 5; ++w) at = fmaf(ht[w], pb[w], at);
                    }
                    const int b = hb * 8 + b8;
                    if (b & 1) {
                        const int m = b >> 1;
                        u0[m] = pk2(ac0, a0);
                        u1[m] = pk2(ac1, a1);
                        u2[m] = pk2(ac2, a2);
                        u3[m] = pk2(ac3, a3);
                        if (doT) ut[m] = pk2(act, at);
                    } else { ac0 = a0; ac1 = a1; ac2 = a2; ac3 = a3; act = at; }
                }
            }
            {   // b = 16 (time column) + S1 slot
                float a0 = h0[0] * ptv[0], a1 = h1[0] * ptv[0];
                float a2 = h2[0] * ptv[0], a3 = h3[0] * ptv[0];
                #pragma unroll
                for (int w = 1; w < 5; ++w) {
                    a0 = fmaf(h0[w], ptv[w], a0);
                    a1 = fmaf(h1[w], ptv[w], a1);
                    a2 = fmaf(h2[w], ptv[w], a2);
                    a3 = fmaf(h3[w], ptv[w], a3);
                }
                u0[8] = pk2(a0, paw[4].x);
                u1[8] = pk2(a1, paw[4].y);
                u2[8] = pk2(a2, paw[4].z);
                u3[8] = pk2(a3, paw[4].w);
                if (doT) {
                    float at = ht[0] * ptv[0];
                    #pragma unroll
                    for (int w = 1; w < 5; ++w) at = fmaf(ht[w], ptv[w], at);
                    ut[8] = pk2(at, ptv[4]);
                }
            }
            // rows 4q..4q+3 = k [72q, 72q+72): contiguous 144 B -> 9 x b128
            char* yr = (char*)ys + row * 656 + q * 144;
            *(uint4*)(yr +   0) = uint4{u0[0], u0[1], u0[2], u0[3]};
            *(uint4*)(yr +  16) = uint4{u0[4], u0[5], u0[6], u0[7]};
            *(uint4*)(yr +  32) = uint4{u0[8], u1[0], u1[1], u1[2]};
            *(uint4*)(yr +  48) = uint4{u1[3], u1[4], u1[5], u1[6]};
            *(uint4*)(yr +  64) = uint4{u1[7], u1[8], u2[0], u2[1]};
            *(uint4*)(yr +  80) = uint4{u2[2], u2[3], u2[4], u2[5]};
            *(uint4*)(yr +  96) = uint4{u2[6], u2[7], u2[8], u3[0]};
            *(uint4*)(yr + 112) = uint4{u3[1], u3[2], u3[3], u3[4]};
            *(uint4*)(yr + 128) = uint4{u3[5], u3[6], u3[7], u3[8]};
            if (doT) {                           // time row a=16 at bytes [576,612)
                char* yt = (char*)ys + row * 656 + 576;
                *(uint4*)(yt +  0) = uint4{ut[0], ut[1], ut[2], ut[3]};
                *(uint4*)(yt + 16) = uint4{ut[4], ut[5], ut[6], ut[7]};
                *(unsigned*)(yt + 32) = ut[8];
            }
        }
        __syncthreads();

        // ---- phase 2: wave = o-quarter; B-frags loaded once; M-tiles {0,16,32,44} ----
        // tile 44 overlaps rows 44..47 (duplicate stores, identical values — benign)
        {
            const float bv = bias[wave * 16 + l15];
            const unsigned short* Bb = Wf + (size_t)(wave * 16 + l15) * KPAD + l4 * 8;
            bf16x8 bfrag[10];
            #pragma unroll
            for (int kk = 0; kk < 10; ++kk)
                bfrag[kk] = *(const bf16x8*)(Bb + kk * 32);
            const int moff[4] = {0, 16, 32, 44};
            #pragma unroll
            for (int mi = 0; mi < 4; ++mi) {
                const char* Ab = (const char*)ys + (moff[mi] + l15) * 656 + l4 * 16;
                f32x4 acc = f32x4{bv, bv, bv, bv};
                #pragma unroll
                for (int kk = 0; kk < 10; ++kk) {
                    bf16x8 af = *(const bf16x8*)(Ab + kk * 64);
                    acc = __builtin_amdgcn_mfma_f32_16x16x32_bf16(af, bfrag[kk], acc, 0, 0, 0);
                }
                const int tg = t0 + moff[mi] + l4 * 4;   // row = l4*4 + reg -> t
                float* op = out + ((size_t)(n * O_DIM + wave * 16 + l15) * J_DIM + j) * T_DIM + tg;
                *(f32x4*)op = acc;
            }
        }
        __syncthreads();   // ys reused by next half's phase 1
    }
}

extern "C" void kernel_launch(void* const* d_in, const int* in_sizes, int n_in,
                              void* d_out, int out_size, void* d_ws, size_t ws_size,
                              hipStream_t stream) {
    const float* x = (const float*)d_in[0];
    const float* W = (const float*)d_in[1];
    const float* b = (const float*)d_in[2];
    float* out = (float*)d_out;
    unsigned short* Wf = (unsigned short*)d_ws;   // 64*328*2 = 41,984 B

    wprep<<<(O_DIM * KPAD + 255) / 256, 256, 0, stream>>>(W, Wf);
    sig_mfma<<<64 * J_DIM, 256, 0, stream>>>(x, Wf, b, out);
}

// Round 19
// 46.649 us; speedup vs baseline: 1.0338x; 1.0338x over previous
//
#include <hip/hip_runtime.h>
#include <hip/hip_bf16.h>

#define J_DIM 25
#define T_DIM 120
#define O_DIM 64
#define KPAD  328        // bf16 per ys/Wf row; 656 B = 41*16 (b128-aligned)
#define TB    64         // t-rows per block; chunks t0 = 0, 56 (8 dup rows, benign)
#define WROWS 68         // staged window rows (row + w <= 67)
#define XPAD  20         // xs row pad (floats); float4 offsets stay 16B-aligned

typedef __attribute__((ext_vector_type(8))) short bf16x8;
typedef __attribute__((ext_vector_type(4))) float f32x4;

__device__ __forceinline__ unsigned f2bf(float f) {
    union { float f; unsigned u; } v; v.f = f;
    return (v.u + 0x7FFFu + ((v.u >> 16) & 1u)) >> 16;
}
__device__ __forceinline__ unsigned pk2(float lo, float hi) {
    __hip_bfloat162 h = __float22bfloat162_rn(float2{lo, hi});
    unsigned u;
    __builtin_memcpy(&u, &h, 4);
    return u;
}
__device__ __forceinline__ float4 sel4(int q, float4 a, float4 b, float4 c, float4 d) {
    float4 s01, s23, r;
    s01.x = (q & 1) ? b.x : a.x; s01.y = (q & 1) ? b.y : a.y;
    s01.z = (q & 1) ? b.z : a.z; s01.w = (q & 1) ? b.w : a.w;
    s23.x = (q & 1) ? d.x : c.x; s23.y = (q & 1) ? d.y : c.y;
    s23.z = (q & 1) ? d.z : c.z; s23.w = (q & 1) ? d.w : c.w;
    r.x = (q & 2) ? s23.x : s01.x; r.y = (q & 2) ? s23.y : s01.y;
    r.z = (q & 2) ? s23.z : s01.z; r.w = (q & 2) ? s23.w : s01.w;
    return r;
}

// ---- W (306x64 f32) -> Wf[o][k], k = 18a + b; b<17: 0.5*W2[a,b]; b==17: W1[a] ----
__global__ void wprep(const float* __restrict__ W, unsigned short* __restrict__ Wf) {
    int i = blockIdx.x * 256 + threadIdx.x;
    if (i >= O_DIM * KPAD) return;
    int o = i / KPAD, k = i % KPAD;
    int a = k / 18, b = k % 18;
    float v = 0.0f;
    if (k < 306) v = (b == 17) ? W[a * O_DIM + o] : 0.5f * W[(17 + 17 * a + b) * O_DIM + o];
    Wf[o * KPAD + k] = (unsigned short)f2bf(v);
}

// ---- main: block = (n, j, 64-row half); 256 threads; flat 2-barrier structure ----
// Lessons: launch_bounds must never clamp VGPR below need (R6/R10 catastrophe);
// phase bodies straight-line, no loop-carried live state (R8/R9/R13 spills);
// B-frag register reuse only inside the short phase-2 scope (R14/R17 proven).
__global__ __launch_bounds__(256, 2) void sig_mfma(
    const float* __restrict__ x, const unsigned short* __restrict__ Wf,
    const float* __restrict__ bias, float* __restrict__ out)
{
    __shared__ float xs[WROWS][XPAD];            // 5,440 B
    __shared__ unsigned short ys[TB * KPAD];     // 41,984 B   (total 47.4 KB)

    const int tid = threadIdx.x;
    const int bid = blockIdx.x;
    const int half = bid & 1;
    const int j = (bid >> 1) % J_DIM;
    const int n = bid / (2 * J_DIM);
    const int t0 = half * 56;                    // halves overlap rows 56..63 (dup stores)
    const int wave = tid >> 6, lane = tid & 63;
    const int l15 = lane & 15, l4 = lane >> 4;

    // ---- stage xs[i][c] = x[n,c,j,clamp(t0-2+i)] ----
    const float* xbase = x + ((size_t)(n * 16) * J_DIM + j) * T_DIM;
    for (int idx = tid; idx < 16 * WROWS; idx += 256) {
        int c = idx / WROWS, i = idx % WROWS;
        int st = min(max(t0 - 2 + i, 0), T_DIM - 1);
        xs[i][c] = xbase[(size_t)c * J_DIM * T_DIM + st];
    }
    // zero pad bytes [608,656) of every row (608-611 re-written by time-row store)
    if (tid < TB * 3) {
        int r = tid / 3, p = tid % 3;
        *(uint4*)((char*)ys + r * 656 + 608 + p * 16) = uint4{0, 0, 0, 0};
    }
    __syncthreads();

    // ---- phase 1: one slot per thread: (row = tid>>2, q = tid&3) -> a = 4q..4q+3 ----
    // All 16 channels loaded ONCE into xall (broadcast 2-way reads); paw derived by
    // q-selects from xall (no extra LDS reads). q==3 also computes time row a=16.
    {
        const int row = tid >> 2, q = tid & 3;
        const int t = t0 + row;
        const int start = max(t - 2, 0), end = min(t + 3, T_DIM);
        const float inv = 1.0f / (float)(end - start - 1);
        const bool doT = (q == 3);
        float ptv[5];
        #pragma unroll
        for (int w = 0; w < 5; ++w) {
            int pcw = min(max(t - 2 + w, 0), T_DIM - 1);
            ptv[w] = (float)(pcw - start) * inv;
        }
        float4 xall[5][4];                       // window row w, channels 4c..4c+3
        #pragma unroll
        for (int w = 0; w < 5; ++w)
            #pragma unroll
            for (int c = 0; c < 4; ++c)
                xall[w][c] = *(const float4*)&xs[row + w][4 * c];

        float4 paw[5];                           // this thread's a-rows 4q..4q+3
        #pragma unroll
        for (int w = 0; w < 5; ++w)
            paw[w] = sel4(q, xall[w][0], xall[w][1], xall[w][2], xall[w][3]);

        float h0[5], h1[5], h2[5], h3[5], ht[5];
        h0[0] = -paw[1].x;           h1[0] = -paw[1].y;           h2[0] = -paw[1].z;           h3[0] = -paw[1].w;
        h0[1] = paw[0].x - paw[2].x; h1[1] = paw[0].y - paw[2].y; h2[1] = paw[0].z - paw[2].z; h3[1] = paw[0].w - paw[2].w;
        h0[2] = paw[1].x - paw[3].x; h1[2] = paw[1].y - paw[3].y; h2[2] = paw[1].z - paw[3].z; h3[2] = paw[1].w - paw[3].w;
        h0[3] = paw[2].x - paw[4].x; h1[3] = paw[2].y - paw[4].y; h2[3] = paw[2].z - paw[4].z; h3[3] = paw[2].w - paw[4].w;
        h0[4] = paw[3].x + paw[4].x; h1[4] = paw[3].y + paw[4].y; h2[4] = paw[3].z + paw[4].z; h3[4] = paw[3].w + paw[4].w;
        if (doT) {
            ht[0] = -ptv[1];
            ht[1] = ptv[0] - ptv[2];
            ht[2] = ptv[1] - ptv[3];
            ht[3] = ptv[2] - ptv[4];
            ht[4] = ptv[3] + ptv[4];
        }

        unsigned u0[9], u1[9], u2[9], u3[9], ut[9];
        float ac0 = 0, ac1 = 0, ac2 = 0, ac3 = 0, act = 0;
        #pragma unroll
        for (int b = 0; b < 16; ++b) {
            float pb[5];
            #pragma unroll
            for (int w = 0; w < 5; ++w) {
                float4 v = xall[w][b >> 2];
                pb[w] = ((b & 3) == 0) ? v.x : ((b & 3) == 1) ? v.y
                      : ((b & 3) == 2) ? v.z : v.w;
            }
            float a0 = h0[0] * pb[0], a1 = h1[0] * pb[0];
            float a2 = h2[0] * pb[0], a3 = h3[0] * pb[0];
            #pragma unroll
            for (int w = 1; w < 5; ++w) {
                a0 = fmaf(h0[w], pb[w], a0);
                a1 = fmaf(h1[w], pb[w], a1);
                a2 = fmaf(h2[w], pb[w], a2);
                a3 = fmaf(h3[w], pb[w], a3);
            }
            float at = 0;
            if (doT) {
                at = ht[0] * pb[0];
                #pragma unroll
                for (int w = 1; w < 5; ++w) at = fmaf(ht[w], pb[w], at);
            }
            if (b & 1) {
                const int m = b >> 1;
                u0[m] = pk2(ac0, a0);
                u1[m] = pk2(ac1, a1);
                u2[m] = pk2(ac2, a2);
                u3[m] = pk2(ac3, a3);
                if (doT) ut[m] = pk2(act, at);
            } else { ac0 = a0; ac1 = a1; ac2 = a2; ac3 = a3; act = at; }
        }
        {   // b = 16 (time column) + S1 slot
            float a0 = h0[0] * ptv[0], a1 = h1[0] * ptv[0];
            float a2 = h2[0] * ptv[0], a3 = h3[0] * ptv[0];
            #pragma unroll
            for (int w = 1; w < 5; ++w) {
                a0 = fmaf(h0[w], ptv[w], a0);
                a1 = fmaf(h1[w], ptv[w], a1);
                a2 = fmaf(h2[w], ptv[w], a2);
                a3 = fmaf(h3[w], ptv[w], a3);
            }
            u0[8] = pk2(a0, paw[4].x);
            u1[8] = pk2(a1, paw[4].y);
            u2[8] = pk2(a2, paw[4].z);
            u3[8] = pk2(a3, paw[4].w);
            if (doT) {
                float at = ht[0] * ptv[0];
                #pragma unroll
                for (int w = 1; w < 5; ++w) at = fmaf(ht[w], ptv[w], at);
                ut[8] = pk2(at, ptv[4]);
            }
        }
        // rows 4q..4q+3 = k [72q, 72q+72): contiguous 144 B -> 9 x b128
        char* yr = (char*)ys + row * 656 + q * 144;
        *(uint4*)(yr +   0) = uint4{u0[0], u0[1], u0[2], u0[3]};
        *(uint4*)(yr +  16) = uint4{u0[4], u0[5], u0[6], u0[7]};
        *(uint4*)(yr +  32) = uint4{u0[8], u1[0], u1[1], u1[2]};
        *(uint4*)(yr +  48) = uint4{u1[3], u1[4], u1[5], u1[6]};
        *(uint4*)(yr +  64) = uint4{u1[7], u1[8], u2[0], u2[1]};
        *(uint4*)(yr +  80) = uint4{u2[2], u2[3], u2[4], u2[5]};
        *(uint4*)(yr +  96) = uint4{u2[6], u2[7], u2[8], u3[0]};
        *(uint4*)(yr + 112) = uint4{u3[1], u3[2], u3[3], u3[4]};
        *(uint4*)(yr + 128) = uint4{u3[5], u3[6], u3[7], u3[8]};
        if (doT) {                               // time row a=16 at bytes [576,612)
            char* yt = (char*)ys + row * 656 + 576;
            *(uint4*)(yt +  0) = uint4{ut[0], ut[1], ut[2], ut[3]};
            *(uint4*)(yt + 16) = uint4{ut[4], ut[5], ut[6], ut[7]};
            *(unsigned*)(yt + 32) = ut[8];
        }
    }
    __syncthreads();

    // ---- phase 2: wave = (M-pair mh, o-half oh); dual-B: each A-read feeds 2 MFMAs ----
    {
        const int mh = wave & 1, oh = wave >> 1;
        float bv0 = bias[oh * 32 + l15];
        float bv1 = bias[oh * 32 + 16 + l15];
        const unsigned short* Bb = Wf + l4 * 8;
        bf16x8 bf0[10], bf1[10];
        #pragma unroll
        for (int kk = 0; kk < 10; ++kk) {
            bf0[kk] = *(const bf16x8*)(Bb + (size_t)(oh * 32 + l15) * KPAD + kk * 32);
            bf1[kk] = *(const bf16x8*)(Bb + (size_t)(oh * 32 + 16 + l15) * KPAD + kk * 32);
        }
        #pragma unroll
        for (int mi = 0; mi < 2; ++mi) {
            const int m = mh * 2 + mi;
            const char* Ab = (const char*)ys + (m * 16 + l15) * 656 + l4 * 16;
            f32x4 acc0 = f32x4{bv0, bv0, bv0, bv0};
            f32x4 acc1 = f32x4{bv1, bv1, bv1, bv1};
            #pragma unroll
            for (int kk = 0; kk < 10; ++kk) {
                bf16x8 af = *(const bf16x8*)(Ab + kk * 64);
                acc0 = __builtin_amdgcn_mfma_f32_16x16x32_bf16(af, bf0[kk], acc0, 0, 0, 0);
                acc1 = __builtin_amdgcn_mfma_f32_16x16x32_bf16(af, bf1[kk], acc1, 0, 0, 0);
            }
            const int tg = t0 + m * 16 + l4 * 4;     // row = l4*4 + reg -> t
            float* op0 = out + ((size_t)(n * O_DIM + oh * 32 + l15) * J_DIM + j) * T_DIM + tg;
            float* op1 = out + ((size_t)(n * O_DIM + oh * 32 + 16 + l15) * J_DIM + j) * T_DIM + tg;
            *(f32x4*)op0 = acc0;
            *(f32x4*)op1 = acc1;
        }
    }
}

extern "C" void kernel_launch(void* const* d_in, const int* in_sizes, int n_in,
                              void* d_out, int out_size, void* d_ws, size_t ws_size,
                              hipStream_t stream) {
    const float* x = (const float*)d_in[0];
    const float* W = (const float*)d_in[1];
    const float* b = (const float*)d_in[2];
    float* out = (float*)d_out;
    unsigned short* Wf = (unsigned short*)d_ws;   // 64*328*2 = 41,984 B

    wprep<<<(O_DIM * KPAD + 255) / 256, 256, 0, stream>>>(W, Wf);
    sig_mfma<<<64 * J_DIM * 2, 256, 0, stream>>>(x, Wf, b, out);
}

// Round 20
// 40.987 us; speedup vs baseline: 1.1767x; 1.1382x over previous
//
#include <hip/hip_runtime.h>
#include <hip/hip_fp16.h>

#define J_DIM 25
#define T_DIM 120
#define O_DIM 64
#define KPAD  328        // f16 per ys/Wf row; 656 B = 41*16 (b128-aligned)
#define TB    64         // t-rows per block; chunks t0 = 0, 56 (8 dup rows, benign)
#define WROWS 68         // staged window rows (row + w <= 67)
#define XPADH 20         // xs row pad (halves): 40 B rows

typedef _Float16 f16x8 __attribute__((ext_vector_type(8)));
typedef __attribute__((ext_vector_type(4))) float f32x4;

__device__ __forceinline__ unsigned h2bits(__half2 h) {
    unsigned u; __builtin_memcpy(&u, &h, 4); return u;
}

// ---- W (306x64 f32) -> Wf[o][k] f16, k = 18a+b; b<17: 0.5*W2[a,b]; b==17: W1[a] ----
__global__ void wprep(const float* __restrict__ W, __half* __restrict__ Wf) {
    int i = blockIdx.x * 256 + threadIdx.x;
    if (i >= O_DIM * KPAD) return;
    int o = i / KPAD, k = i % KPAD;
    int a = k / 18, b = k % 18;
    float v = 0.0f;
    if (k < 306) v = (b == 17) ? W[a * O_DIM + o] : 0.5f * W[(17 + 17 * a + b) * O_DIM + o];
    Wf[o * KPAD + k] = __float2half(v);
}

// ---- main: block = (n, j, 64-row half); 256 threads; flat 2-barrier structure ----
// Lessons: launch_bounds must never clamp VGPR below need (R6/R10 catastrophe);
// phase bodies flat, no cross-phase live state in loops (R8/R9/R13 spills);
// no runtime indexing into register arrays (rule #20) — q-pair re-read from LDS.
__global__ __launch_bounds__(256, 3) void sig_mfma(
    const float* __restrict__ x, const __half* __restrict__ Wf,
    const float* __restrict__ bias, float* __restrict__ out)
{
    __shared__ __half xs[WROWS][XPADH];          // 2,720 B
    __shared__ __half ys[TB * KPAD];             // 41,984 B  (total 44.7 KB -> 3 blk/CU)

    const int tid = threadIdx.x;
    const int bid = blockIdx.x;
    const int half_ = bid & 1;
    const int j = (bid >> 1) % J_DIM;
    const int n = bid / (2 * J_DIM);
    const int t0 = half_ * 56;                   // halves overlap rows 56..63 (dup stores)
    const int wave = tid >> 6, lane = tid & 63;
    const int l15 = lane & 15, l4 = lane >> 4;

    // ---- stage xs[i][c] = (f16) x[n,c,j,clamp(t0-2+i)] ----
    const float* xbase = x + ((size_t)(n * 16) * J_DIM + j) * T_DIM;
    for (int idx = tid; idx < 16 * WROWS; idx += 256) {
        int c = idx / WROWS, i = idx % WROWS;
        int st = min(max(t0 - 2 + i, 0), T_DIM - 1);
        xs[i][c] = __float2half(xbase[(size_t)c * J_DIM * T_DIM + st]);
    }
    // zero pad bytes [608,656) of every row (608-611 re-written by time-row store)
    if (tid < TB * 3) {
        int r = tid / 3, p = tid % 3;
        *(uint4*)((char*)ys + r * 656 + 608 + p * 16) = uint4{0, 0, 0, 0};
    }
    __syncthreads();

    // ---- phase 1: 512 slots (row 0..63, q 0..7); thread does slots tid, tid+256 ----
    // S2[a,b] = sum_w h_w[a]*p_w[b], h = (-p1, p0-p2, p1-p3, p2-p4, p3+p4)
    // Packed f16: acc{S2[a,2b2],S2[a,2b2+1]} via v_pk_fma_f16; h broadcast, p natural.
    #pragma unroll 1
    for (int s = tid; s < TB * 8; s += 256) {
        const int row = s >> 3, q = s & 7;
        const int t = t0 + row;
        const int start = max(t - 2, 0), end = min(t + 3, T_DIM);
        const float inv = 1.0f / (float)(end - start - 1);
        float ptvf[5];
        #pragma unroll
        for (int w = 0; w < 5; ++w) {
            int pcw = min(max(t - 2 + w, 0), T_DIM - 1);
            ptvf[w] = (float)(pcw - start) * inv;
        }
        __half2 ptvb[5];
        #pragma unroll
        for (int w = 0; w < 5; ++w) ptvb[w] = __float2half2_rn(ptvf[w]);

        // own a-row pair {p[2q], p[2q+1]} per window row (direct LDS read, runtime q ok)
        __half2 pr[5];
        #pragma unroll
        for (int w = 0; w < 5; ++w)
            pr[w] = *(const __half2*)&xs[row + w][2 * q];
        __half2 hp[5];                           // {h0,h1}[w] packed
        hp[0] = __hneg2(pr[1]);
        hp[1] = __hsub2(pr[0], pr[2]);
        hp[2] = __hsub2(pr[1], pr[3]);
        hp[3] = __hsub2(pr[2], pr[4]);
        hp[4] = __hadd2(pr[3], pr[4]);
        __half2 h0b[5], h1b[5];
        #pragma unroll
        for (int w = 0; w < 5; ++w) {
            h0b[w] = __low2half2(hp[w]);
            h1b[w] = __high2half2(hp[w]);
        }
        // full-channel b-pairs (compile-time indexed only — rule #20)
        __half2 xw[5][8];
        #pragma unroll
        for (int w = 0; w < 5; ++w)
            #pragma unroll
            for (int c2 = 0; c2 < 8; ++c2)
                xw[w][c2] = *(const __half2*)&xs[row + w][2 * c2];

        unsigned u0[9], u1[9];
        #pragma unroll
        for (int b2 = 0; b2 < 8; ++b2) {
            __half2 a0 = __hmul2(h0b[0], xw[0][b2]);
            __half2 a1 = __hmul2(h1b[0], xw[0][b2]);
            #pragma unroll
            for (int w = 1; w < 5; ++w) {
                a0 = __hfma2(h0b[w], xw[w][b2], a0);
                a1 = __hfma2(h1b[w], xw[w][b2], a1);
            }
            u0[b2] = h2bits(a0);
            u1[b2] = h2bits(a1);
        }
        {   // b-pair (16,17): {S2[a,16], S1[a]=p4[a]}
            __half2 a16 = __hmul2(hp[0], ptvb[0]);
            #pragma unroll
            for (int w = 1; w < 5; ++w) a16 = __hfma2(hp[w], ptvb[w], a16);
            u0[8] = h2bits(__halves2half2(__low2half(a16),  __low2half(pr[4])));
            u1[8] = h2bits(__halves2half2(__high2half(a16), __high2half(pr[4])));
        }
        // rows 2q,2q+1: bytes [72q, 72q+72) contiguous -> 9 x b64
        char* yr = (char*)ys + row * 656 + 72 * q;
        *(uint2*)(yr +  0) = uint2{u0[0], u0[1]};
        *(uint2*)(yr +  8) = uint2{u0[2], u0[3]};
        *(uint2*)(yr + 16) = uint2{u0[4], u0[5]};
        *(uint2*)(yr + 24) = uint2{u0[6], u0[7]};
        *(uint2*)(yr + 32) = uint2{u0[8], u1[0]};
        *(uint2*)(yr + 40) = uint2{u1[1], u1[2]};
        *(uint2*)(yr + 48) = uint2{u1[3], u1[4]};
        *(uint2*)(yr + 56) = uint2{u1[5], u1[6]};
        *(uint2*)(yr + 64) = uint2{u1[7], u1[8]};

        if (q == 0) {                            // time row a=16: k 288..305, bytes [576,612)
            __half2 htb[5];
            htb[0] = __float2half2_rn(-ptvf[1]);
            htb[1] = __float2half2_rn(ptvf[0] - ptvf[2]);
            htb[2] = __float2half2_rn(ptvf[1] - ptvf[3]);
            htb[3] = __float2half2_rn(ptvf[2] - ptvf[4]);
            htb[4] = __float2half2_rn(ptvf[3] + ptvf[4]);
            unsigned ut[9];
            #pragma unroll
            for (int b2 = 0; b2 < 8; ++b2) {
                __half2 a = __hmul2(htb[0], xw[0][b2]);
                #pragma unroll
                for (int w = 1; w < 5; ++w) a = __hfma2(htb[w], xw[w][b2], a);
                ut[b2] = h2bits(a);
            }
            {   // {S2[16,16], S1[16]=ptv4}
                __half2 a = __hmul2(htb[0], ptvb[0]);
                #pragma unroll
                for (int w = 1; w < 5; ++w) a = __hfma2(htb[w], ptvb[w], a);
                ut[8] = h2bits(__halves2half2(__low2half(a), __float2half(ptvf[4])));
            }
            char* yt = (char*)ys + row * 656 + 576;
            *(uint2*)(yt +  0) = uint2{ut[0], ut[1]};
            *(uint2*)(yt +  8) = uint2{ut[2], ut[3]};
            *(uint2*)(yt + 16) = uint2{ut[4], ut[5]};
            *(uint2*)(yt + 24) = uint2{ut[6], ut[7]};
            *(unsigned*)(yt + 32) = ut[8];
        }
    }
    __syncthreads();

    // ---- phase 2: wave = o-quarter; B-frags loaded once, reused over 4 M-tiles ----
    {
        const float bv = bias[wave * 16 + l15];
        const __half* Bb = Wf + (size_t)(wave * 16 + l15) * KPAD + l4 * 8;
        f16x8 bfrag[10];
        #pragma unroll
        for (int kk = 0; kk < 10; ++kk)
            bfrag[kk] = *(const f16x8*)(Bb + kk * 32);
        #pragma unroll
        for (int mi = 0; mi < 4; ++mi) {
            const char* Ab = (const char*)ys + (mi * 16 + l15) * 656 + l4 * 16;
            f32x4 acc = f32x4{bv, bv, bv, bv};
            #pragma unroll
            for (int kk = 0; kk < 10; ++kk) {
                f16x8 af = *(const f16x8*)(Ab + kk * 64);
                acc = __builtin_amdgcn_mfma_f32_16x16x32_f16(af, bfrag[kk], acc, 0, 0, 0);
            }
            const int tg = t0 + mi * 16 + l4 * 4;    // row = l4*4 + reg -> t
            float* op = out + ((size_t)(n * O_DIM + wave * 16 + l15) * J_DIM + j) * T_DIM + tg;
            *(f32x4*)op = acc;
        }
    }
}

extern "C" void kernel_launch(void* const* d_in, const int* in_sizes, int n_in,
                              void* d_out, int out_size, void* d_ws, size_t ws_size,
                              hipStream_t stream) {
    const float* x = (const float*)d_in[0];
    const float* W = (const float*)d_in[1];
    const float* b = (const float*)d_in[2];
    float* out = (float*)d_out;
    __half* Wf = (__half*)d_ws;                  // 64*328*2 = 41,984 B

    wprep<<<(O_DIM * KPAD + 255) / 256, 256, 0, stream>>>(W, Wf);
    sig_mfma<<<64 * J_DIM * 2, 256, 0, stream>>>(x, Wf, b, out);
}

// Round 21
// 39.351 us; speedup vs baseline: 1.2256x; 1.0416x over previous
//
#include <hip/hip_runtime.h>
#include <hip/hip_fp16.h>

#define J_DIM 25
#define T_DIM 120
#define O_DIM 64
#define KPAD  328        // f16 per ys/Wf row; 656 B = 41*16 (b128-aligned)
#define TB    64         // t-rows per block; chunks t0 = 0, 56 (8 dup rows, benign)
#define WROWS 68         // staged window rows (row + w <= 67)
#define XPADH 20         // xs row pad (halves): 40 B rows

typedef _Float16 f16x8 __attribute__((ext_vector_type(8)));
typedef __attribute__((ext_vector_type(4))) float f32x4;

__device__ __forceinline__ unsigned h2bits(__half2 h) {
    unsigned u; __builtin_memcpy(&u, &h, 4); return u;
}
__device__ __forceinline__ __half2 bits2h(unsigned u) {
    __half2 h; __builtin_memcpy(&h, &u, 4); return h;
}
// select one of 4 half2 by q (0..3): 3 v_cndmask, no LDS, no runtime reg-indexing
__device__ __forceinline__ __half2 sel4h(int q, __half2 a, __half2 b, __half2 c, __half2 d) {
    unsigned s01 = (q & 1) ? h2bits(b) : h2bits(a);
    unsigned s23 = (q & 1) ? h2bits(d) : h2bits(c);
    return bits2h((q & 2) ? s23 : s01);
}

// ---- W (306x64 f32) -> Wf[o][k] f16, k = 18a+b; b<17: 0.5*W2[a,b]; b==17: W1[a] ----
__global__ void wprep(const float* __restrict__ W, __half* __restrict__ Wf) {
    int i = blockIdx.x * 256 + threadIdx.x;
    if (i >= O_DIM * KPAD) return;
    int o = i / KPAD, k = i % KPAD;
    int a = k / 18, b = k % 18;
    float v = 0.0f;
    if (k < 306) v = (b == 17) ? W[a * O_DIM + o] : 0.5f * W[(17 + 17 * a + b) * O_DIM + o];
    Wf[o * KPAD + k] = __float2half(v);
}

// ---- main: block = (n, j, 64-row half); 256 threads; flat 2-barrier structure ----
// Lessons: launch_bounds must never clamp VGPR below need (R6/R10 catastrophe);
// phase bodies flat, straight-line, no cross-phase live state in loops
// (R8/R9/R13 spills); no runtime indexing into register arrays (rule #20).
__global__ __launch_bounds__(256, 2) void sig_mfma(
    const float* __restrict__ x, const __half* __restrict__ Wf,
    const float* __restrict__ bias, float* __restrict__ out)
{
    __shared__ __half xs[WROWS][XPADH];          // 2,720 B
    __shared__ __half ys[TB * KPAD];             // 41,984 B  (total 44.7 KB -> 3 blk/CU)

    const int tid = threadIdx.x;
    const int bid = blockIdx.x;
    const int half_ = bid & 1;
    const int j = (bid >> 1) % J_DIM;
    const int n = bid / (2 * J_DIM);
    const int t0 = half_ * 56;                   // halves overlap rows 56..63 (dup stores)
    const int wave = tid >> 6, lane = tid & 63;
    const int l15 = lane & 15, l4 = lane >> 4;

    // ---- stage xs[i][c] = (f16) x[n,c,j,clamp(t0-2+i)] ----
    const float* xbase = x + ((size_t)(n * 16) * J_DIM + j) * T_DIM;
    for (int idx = tid; idx < 16 * WROWS; idx += 256) {
        int c = idx / WROWS, i = idx % WROWS;
        int st = min(max(t0 - 2 + i, 0), T_DIM - 1);
        xs[i][c] = __float2half(xbase[(size_t)c * J_DIM * T_DIM + st]);
    }
    // zero pad bytes [608,656) of every row (608-611 re-written by time-row store)
    if (tid < TB * 3) {
        int r = tid / 3, p = tid % 3;
        *(uint4*)((char*)ys + r * 656 + 608 + p * 16) = uint4{0, 0, 0, 0};
    }
    __syncthreads();

    // ---- phase 1: thread = (row = tid>>2, qg = tid&3); q = qg and qg+4, SAME row ----
    // S2[a,b] = sum_w h_w[a]*p_w[b], h = (-p1, p0-p2, p1-p3, p2-p4, p3+p4)
    // xw loaded ONCE per thread; a-row pairs derived by cndmask selects from xw.
    {
        const int row = tid >> 2, qg = tid & 3;
        const int t = t0 + row;
        const int start = max(t - 2, 0), end = min(t + 3, T_DIM);
        const float inv = 1.0f / (float)(end - start - 1);
        float ptvf[5];
        #pragma unroll
        for (int w = 0; w < 5; ++w) {
            int pcw = min(max(t - 2 + w, 0), T_DIM - 1);
            ptvf[w] = (float)(pcw - start) * inv;
        }
        __half2 ptvb[5];
        #pragma unroll
        for (int w = 0; w < 5; ++w) ptvb[w] = __float2half2_rn(ptvf[w]);

        // full 16-channel window, loaded once (broadcast-friendly: 4 lanes/row)
        __half2 xw[5][8];
        #pragma unroll
        for (int w = 0; w < 5; ++w)
            #pragma unroll
            for (int c2 = 0; c2 < 8; ++c2)
                xw[w][c2] = *(const __half2*)&xs[row + w][2 * c2];

        // ---------- A-pair: q = qg, a-rows {2qg, 2qg+1} ----------
        {
            __half2 pr[5];
            #pragma unroll
            for (int w = 0; w < 5; ++w)
                pr[w] = sel4h(qg, xw[w][0], xw[w][1], xw[w][2], xw[w][3]);
            __half2 hp[5];
            hp[0] = __hneg2(pr[1]);
            hp[1] = __hsub2(pr[0], pr[2]);
            hp[2] = __hsub2(pr[1], pr[3]);
            hp[3] = __hsub2(pr[2], pr[4]);
            hp[4] = __hadd2(pr[3], pr[4]);
            __half2 h0b[5], h1b[5];
            #pragma unroll
            for (int w = 0; w < 5; ++w) {
                h0b[w] = __low2half2(hp[w]);
                h1b[w] = __high2half2(hp[w]);
            }
            unsigned u0[9], u1[9];
            #pragma unroll
            for (int b2 = 0; b2 < 8; ++b2) {
                __half2 a0 = __hmul2(h0b[0], xw[0][b2]);
                __half2 a1 = __hmul2(h1b[0], xw[0][b2]);
                #pragma unroll
                for (int w = 1; w < 5; ++w) {
                    a0 = __hfma2(h0b[w], xw[w][b2], a0);
                    a1 = __hfma2(h1b[w], xw[w][b2], a1);
                }
                u0[b2] = h2bits(a0);
                u1[b2] = h2bits(a1);
            }
            {   // b-pair (16,17): {S2[a,16], S1[a]=p4[a]}
                __half2 a16 = __hmul2(hp[0], ptvb[0]);
                #pragma unroll
                for (int w = 1; w < 5; ++w) a16 = __hfma2(hp[w], ptvb[w], a16);
                u0[8] = h2bits(__halves2half2(__low2half(a16),  __low2half(pr[4])));
                u1[8] = h2bits(__halves2half2(__high2half(a16), __high2half(pr[4])));
            }
            char* yr = (char*)ys + row * 656 + 72 * qg;      // rows 2qg,2qg+1
            *(uint2*)(yr +  0) = uint2{u0[0], u0[1]};
            *(uint2*)(yr +  8) = uint2{u0[2], u0[3]};
            *(uint2*)(yr + 16) = uint2{u0[4], u0[5]};
            *(uint2*)(yr + 24) = uint2{u0[6], u0[7]};
            *(uint2*)(yr + 32) = uint2{u0[8], u1[0]};
            *(uint2*)(yr + 40) = uint2{u1[1], u1[2]};
            *(uint2*)(yr + 48) = uint2{u1[3], u1[4]};
            *(uint2*)(yr + 56) = uint2{u1[5], u1[6]};
            *(uint2*)(yr + 64) = uint2{u1[7], u1[8]};
        }

        // ---------- B-pair: q = qg+4, a-rows {2qg+8, 2qg+9} ----------
        {
            __half2 pr[5];
            #pragma unroll
            for (int w = 0; w < 5; ++w)
                pr[w] = sel4h(qg, xw[w][4], xw[w][5], xw[w][6], xw[w][7]);
            __half2 hp[5];
            hp[0] = __hneg2(pr[1]);
            hp[1] = __hsub2(pr[0], pr[2]);
            hp[2] = __hsub2(pr[1], pr[3]);
            hp[3] = __hsub2(pr[2], pr[4]);
            hp[4] = __hadd2(pr[3], pr[4]);
            __half2 h0b[5], h1b[5];
            #pragma unroll
            for (int w = 0; w < 5; ++w) {
                h0b[w] = __low2half2(hp[w]);
                h1b[w] = __high2half2(hp[w]);
            }
            unsigned u0[9], u1[9];
            #pragma unroll
            for (int b2 = 0; b2 < 8; ++b2) {
                __half2 a0 = __hmul2(h0b[0], xw[0][b2]);
                __half2 a1 = __hmul2(h1b[0], xw[0][b2]);
                #pragma unroll
                for (int w = 1; w < 5; ++w) {
                    a0 = __hfma2(h0b[w], xw[w][b2], a0);
                    a1 = __hfma2(h1b[w], xw[w][b2], a1);
                }
                u0[b2] = h2bits(a0);
                u1[b2] = h2bits(a1);
            }
            {   // b-pair (16,17)
                __half2 a16 = __hmul2(hp[0], ptvb[0]);
                #pragma unroll
                for (int w = 1; w < 5; ++w) a16 = __hfma2(hp[w], ptvb[w], a16);
                u0[8] = h2bits(__halves2half2(__low2half(a16),  __low2half(pr[4])));
                u1[8] = h2bits(__halves2half2(__high2half(a16), __high2half(pr[4])));
            }
            char* yr = (char*)ys + row * 656 + 72 * qg + 288;  // rows 2qg+8, 2qg+9
            *(uint2*)(yr +  0) = uint2{u0[0], u0[1]};
            *(uint2*)(yr +  8) = uint2{u0[2], u0[3]};
            *(uint2*)(yr + 16) = uint2{u0[4], u0[5]};
            *(uint2*)(yr + 24) = uint2{u0[6], u0[7]};
            *(uint2*)(yr + 32) = uint2{u0[8], u1[0]};
            *(uint2*)(yr + 40) = uint2{u1[1], u1[2]};
            *(uint2*)(yr + 48) = uint2{u1[3], u1[4]};
            *(uint2*)(yr + 56) = uint2{u1[5], u1[6]};
            *(uint2*)(yr + 64) = uint2{u1[7], u1[8]};
        }

        // ---------- time row a=16 (once per row, qg==0) ----------
        if (qg == 0) {
            __half2 htb[5];
            htb[0] = __float2half2_rn(-ptvf[1]);
            htb[1] = __float2half2_rn(ptvf[0] - ptvf[2]);
            htb[2] = __float2half2_rn(ptvf[1] - ptvf[3]);
            htb[3] = __float2half2_rn(ptvf[2] - ptvf[4]);
            htb[4] = __float2half2_rn(ptvf[3] + ptvf[4]);
            unsigned ut[9];
            #pragma unroll
            for (int b2 = 0; b2 < 8; ++b2) {
                __half2 a = __hmul2(htb[0], xw[0][b2]);
                #pragma unroll
                for (int w = 1; w < 5; ++w) a = __hfma2(htb[w], xw[w][b2], a);
                ut[b2] = h2bits(a);
            }
            {   // {S2[16,16], S1[16]=ptv4}
                __half2 a = __hmul2(htb[0], ptvb[0]);
                #pragma unroll
                for (int w = 1; w < 5; ++w) a = __hfma2(htb[w], ptvb[w], a);
                ut[8] = h2bits(__halves2half2(__low2half(a), __float2half(ptvf[4])));
            }
            char* yt = (char*)ys + row * 656 + 576;          // bytes [576,612)
            *(uint2*)(yt +  0) = uint2{ut[0], ut[1]};
            *(uint2*)(yt +  8) = uint2{ut[2], ut[3]};
            *(uint2*)(yt + 16) = uint2{ut[4], ut[5]};
            *(uint2*)(yt + 24) = uint2{ut[6], ut[7]};
            *(unsigned*)(yt + 32) = ut[8];
        }
    }
    __syncthreads();

    // ---- phase 2: wave = o-quarter; B-frags loaded once, reused over 4 M-tiles ----
    {
        const float bv = bias[wave * 16 + l15];
        const __half* Bb = Wf + (size_t)(wave * 16 + l15) * KPAD + l4 * 8;
        f16x8 bfrag[10];
        #pragma unroll
        for (int kk = 0; kk < 10; ++kk)
            bfrag[kk] = *(const f16x8*)(Bb + kk * 32);
        #pragma unroll
        for (int mi = 0; mi < 4; ++mi) {
            const char* Ab = (const char*)ys + (mi * 16 + l15) * 656 + l4 * 16;
            f32x4 acc = f32x4{bv, bv, bv, bv};
            #pragma unroll
            for (int kk = 0; kk < 10; ++kk) {
                f16x8 af = *(const f16x8*)(Ab + kk * 64);
                acc = __builtin_amdgcn_mfma_f32_16x16x32_f16(af, bfrag[kk], acc, 0, 0, 0);
            }
            const int tg = t0 + mi * 16 + l4 * 4;    // row = l4*4 + reg -> t
            float* op = out + ((size_t)(n * O_DIM + wave * 16 + l15) * J_DIM + j) * T_DIM + tg;
            *(f32x4*)op = acc;
        }
    }
}

extern "C" void kernel_launch(void* const* d_in, const int* in_sizes, int n_in,
                              void* d_out, int out_size, void* d_ws, size_t ws_size,
                              hipStream_t stream) {
    const float* x = (const float*)d_in[0];
    const float* W = (const float*)d_in[1];
    const float* b = (const float*)d_in[2];
    float* out = (float*)d_out;
    __half* Wf = (__half*)d_ws;                  // 64*328*2 = 41,984 B

    wprep<<<(O_DIM * KPAD + 255) / 256, 256, 0, stream>>>(W, Wf);
    sig_mfma<<<64 * J_DIM * 2, 256, 0, stream>>>(x, Wf, b, out);
}